// Round 10
// baseline (2838.024 us; speedup 1.0000x reference)
//
#include <hip/hip_runtime.h>
#include <stdint.h>

// ---------- types ----------
typedef __attribute__((ext_vector_type(4))) int   int4v;   // 4 dwords = 16 int8
typedef __attribute__((ext_vector_type(4))) float f32x4;

#define K_DIM 4096
#define N_DIM 11008
#define M_DIM 8192
#define BM 256
#define BN 256
#define BKB 128             // K-bytes (= K elems, int8) per tile
#define NT (K_DIM / BKB)    // 32 K-tiles
#define MT2 (M_DIM / BM)    // 32
#define NT2 (N_DIM / BN)    // 43

// ---------- x quantization: per-row int8, s_r = max|x_row|/127 ----------
__global__ __launch_bounds__(256) void quant_x_kernel(
    const float* __restrict__ x, unsigned char* __restrict__ xq,
    float* __restrict__ srow)
{
    const int row = blockIdx.x;                       // 0..8191
    const float4* xr = (const float4*)(x + (size_t)row * K_DIM);
    float4 v[4];
    float m = 0.f;
    #pragma unroll
    for (int i = 0; i < 4; ++i) {
        v[i] = xr[threadIdx.x + 256 * i];
        m = fmaxf(m, fmaxf(fmaxf(fabsf(v[i].x), fabsf(v[i].y)),
                           fmaxf(fabsf(v[i].z), fabsf(v[i].w))));
    }
    #pragma unroll
    for (int off = 32; off; off >>= 1) m = fmaxf(m, __shfl_xor(m, off, 64));
    __shared__ float wmax[4];
    if ((threadIdx.x & 63) == 0) wmax[threadIdx.x >> 6] = m;
    __syncthreads();
    const float mb  = fmaxf(fmaxf(wmax[0], wmax[1]), fmaxf(wmax[2], wmax[3]));
    const float s   = (mb > 0.f) ? mb * (1.f / 127.f) : 1.f;
    const float inv = (mb > 0.f) ? 127.f / mb : 0.f;
    if (threadIdx.x == 0) srow[row] = s;
    uint32_t* oq = (uint32_t*)(xq + (size_t)row * K_DIM);
    #pragma unroll
    for (int i = 0; i < 4; ++i) {
        int a = __float2int_rn(v[i].x * inv), b = __float2int_rn(v[i].y * inv);
        int c = __float2int_rn(v[i].z * inv), d = __float2int_rn(v[i].w * inv);
        oq[threadIdx.x + 256 * i] =
            (a & 0xff) | ((b & 0xff) << 8) | ((c & 0xff) << 16) | ((d & 0xff) << 24);
    }
}

// ---------- w: int32 -> int8 (exact), 8/thread ----------
__global__ void cvt_w8_kernel(const int* __restrict__ w,
                              uint2* __restrict__ wq, int n8) {
    int i = blockIdx.x * blockDim.x + threadIdx.x;
    if (i >= n8) return;
    const int4* p = (const int4*)w + 2 * (size_t)i;
    int4 a = p[0], b = p[1];
    uint32_t lo = (a.x & 0xff) | ((a.y & 0xff) << 8) | ((a.z & 0xff) << 16) | ((a.w & 0xff) << 24);
    uint32_t hi = (b.x & 0xff) | ((b.y & 0xff) << 8) | ((b.z & 0xff) << 16) | ((b.w & 0xff) << 24);
    wq[i] = (uint2){lo, hi};
}

// ---------- 256x256 int8 GEMM, single-buffer ring, 2 blocks/CU ----------
#define GLDS16(gsrc, ldst)                                                       \
    __builtin_amdgcn_global_load_lds(                                            \
        (const __attribute__((address_space(1))) void*)(gsrc),                   \
        (__attribute__((address_space(3))) void*)(ldst), 16, 0, 0)

#define SCHED0()  __builtin_amdgcn_sched_barrier(0)
#define BARRIER() __builtin_amdgcn_s_barrier()
#define VMCNT(n)  asm volatile("s_waitcnt vmcnt(" #n ")" ::: "memory")

__global__ __launch_bounds__(512, 4) void gemm2_kernel(
    const unsigned char* __restrict__ xq,   // [8192][4096] int8
    const unsigned char* __restrict__ wq,   // [11008][4096] int8
    const float* __restrict__ srow,         // [8192] per-row x scale
    const float* __restrict__ scale,        // [1]
    const float* __restrict__ bias,         // [11008]
    float* __restrict__ out)                // [8192][11008]
{
    // Single 64 KiB buffer: RA0 @0, RA1 @16K, RB0 @32K, RB1 @48K.
    __shared__ unsigned char sm[65536];
    char* smc = (char*)sm;

    const int T  = threadIdx.x;
    const int l  = T & 63;
    const int wv = T >> 6;
    const int wm = wv >> 2;      // 0..1
    const int wn = wv & 3;       // 0..3

    // XCD-aware, bn-major grid map (B panel shared across XCDs via L3)
    const int orig = blockIdx.x;
    const int xcd  = orig & 7;
    const int p    = orig >> 3;          // 0..171
    const int bm   = xcd * 4 + (p & 3);  // 0..31
    const int bn   = p >> 2;             // 0..42
    const size_t rowM0 = (size_t)bm * BM;
    const size_t rowN0 = (size_t)bn * BN;

    // ---- staging precompute (pre-swizzled global source, linear LDS dest) ----
    const int rowT = T >> 3;                                          // 0..63
    const int colT = (((T & 7) * 16) ^ ((rowT & 7) << 4));            // BYTES
    const unsigned char* pAg = xq + (rowM0 + rowT) * (size_t)K_DIM + colT;
    const unsigned char* pBg = wq + (rowN0 + ((rowT >> 5) << 6) + (rowT & 31)) * (size_t)K_DIM + colT;

    auto stageA = [&](int Q, int kt) {
        #pragma unroll
        for (int c = 0; c < 2; ++c) {
            const unsigned char* src = pAg + (size_t)(c * 128 + Q * 64) * K_DIM + (size_t)kt * BKB;
            char* dst = smc + Q * 16384 + c * 8192 + T * 16;
            GLDS16(src, dst);
        }
    };
    auto stageB = [&](int Q, int kt) {
        #pragma unroll
        for (int c = 0; c < 2; ++c) {
            const unsigned char* src = pBg + (size_t)(c * 128 + Q * 32) * K_DIM + (size_t)kt * BKB;
            char* dst = smc + 32768 + Q * 16384 + c * 8192 + T * 16;
            GLDS16(src, dst);
        }
    };

    // ---- ds_read precompute (16x16x64 i8 fragments) ----
    const int sw     = (l & 7) << 4;
    const int inrow0 = (l >> 4) * 16;
    const int lowk0  = inrow0 ^ sw;            // k 0..63
    const int lowk1  = (64 + inrow0) ^ sw;     // k 64..127
    const int arow   = wm * 64 + (l & 15);
    const int brow   = wn * 32 + (l & 15);

    int4v acc[8][4];
    #pragma unroll
    for (int i = 0; i < 8; ++i)
        #pragma unroll
        for (int j = 0; j < 4; ++j)
            acc[i][j] = (int4v){0, 0, 0, 0};

    int4v Ah[4][2];   // current A quadrant (q0 at p0/p1, q1 at p2/p3)
    int4v Bh[4][2];   // Bh[0..1]=B0(cur), Bh[2..3]=B1(cur)

#define READ_A(base)                                                             \
    _Pragma("unroll")                                                            \
    for (int im = 0; im < 4; ++im) {                                             \
        Ah[im][0] = *(const int4v*)((base) + (arow + im * 16) * 128 + lowk0);    \
        Ah[im][1] = *(const int4v*)((base) + (arow + im * 16) * 128 + lowk1);    \
    }
#define READ_B(base, f0)                                                         \
    _Pragma("unroll")                                                            \
    for (int f = 0; f < 2; ++f) {                                                \
        Bh[(f0) + f][0] = *(const int4v*)((base) + (brow + f * 16) * 128 + lowk0); \
        Bh[(f0) + f][1] = *(const int4v*)((base) + (brow + f * 16) * 128 + lowk1); \
    }
#define MFMAQ(mi, ni)                                                            \
    __builtin_amdgcn_s_setprio(1);                                               \
    _Pragma("unroll")                                                            \
    for (int im = 0; im < 4; ++im)                                               \
        _Pragma("unroll")                                                        \
        for (int jn = 0; jn < 2; ++jn)                                           \
            _Pragma("unroll")                                                    \
            for (int kk = 0; kk < 2; ++kk)                                       \
                acc[(mi) + im][(ni) + jn] = __builtin_amdgcn_mfma_i32_16x16x64_i8( \
                    Ah[im][kk], Bh[(ni) + jn][kk], acc[(mi) + im][(ni) + jn], 0, 0, 0); \
    __builtin_amdgcn_s_setprio(0);

    // Region lifecycle (tile E, stages target E+1):
    //   RA0: read(reg) @E-1 p3-tail -> stage @E p0-head -> read @E p3-tail
    //   RB0: same as RA0
    //   RB1: read @E p0-head      -> stage @E p1-head -> read @E+1 p0-head
    //   RA1: read @E p1-tail      -> stage @E p3-head -> read @E+1 p1-tail
    // Every stage/read pair is separated by >=1 barrier; gates are counted
    // vmcnt before the separating barrier (gate -> barrier -> read).
    // Steady queue: enter p0 with [A1(E):2].
#define TILE_BODY(EE, ST)                                                        \
    /* p0-head (window boundary->BAR0) */                                        \
    READ_B(smc + 49152, 2);                 /* B1(E) -> Bh23 */                  \
    if (ST) { stageA(0, (EE) + 1); stageB(0, (EE) + 1); }                        \
    BARRIER(); SCHED0();                                                         \
    MFMAQ(0, 0);                            /* Aq0 x B0 */                       \
    if (ST) VMCNT(4); else VMCNT(0);        /* drain A1(E) */                    \
    SCHED0();                                                                    \
    /* p1-head */                                                                \
    if (ST) stageB(1, (EE) + 1);                                                 \
    BARRIER(); SCHED0();                                                         \
    MFMAQ(0, 2);                            /* Aq0 x B1 */                       \
    READ_A(smc + 16384);                    /* A1(E) -> Ah */                    \
    SCHED0();                                                                    \
    /* p2 (no stage) */                                                          \
    BARRIER(); SCHED0();                                                         \
    MFMAQ(4, 0);                            /* Aq1 x B0 */                       \
    if (ST) VMCNT(2); else VMCNT(0);        /* drain A0,B0(E+1) */               \
    SCHED0();                                                                    \
    /* p3-head */                                                                \
    if (ST) stageA(1, (EE) + 1);                                                 \
    BARRIER(); SCHED0();                                                         \
    MFMAQ(4, 2);                            /* Aq1 x B1 */                       \
    if (ST) { READ_A(smc); READ_B(smc + 32768, 0); }  /* A0,B0(E+1) */           \
    if (ST) VMCNT(2); else VMCNT(0);        /* drain B1(E+1) */                  \
    BARRIER(); SCHED0();                    /* boundary */

    // ---- prologue: stage tile0 in FIFO order A0,B0,B1,A1 (8 loads) ----
    stageA(0, 0); stageB(0, 0); stageB(1, 0); stageA(1, 0);
    VMCNT(4);                        // A0,B0(0) resident
    BARRIER(); SCHED0();
    READ_A(smc);                     // Aq0(0)
    READ_B(smc + 32768, 0);          // B0(0)
    VMCNT(2);                        // B1(0) resident; leaves A1(0):2
    BARRIER(); SCHED0();

    for (int kt = 0; kt < NT; ++kt) {
        const bool st = (kt + 1 < NT);
        TILE_BODY(kt, st);
    }

    // ---- epilogue: y = acc * s_r * s_w + bias ----
    const float s = scale[0];
    #pragma unroll
    for (int fm = 0; fm < 8; ++fm) {
        const size_t row0 = rowM0 + wm * 128 + fm * 16 + (l >> 4) * 4;
        const float4 sr4 = *(const float4*)(srow + row0);
        #pragma unroll
        for (int fn = 0; fn < 4; ++fn) {
            const int col = (int)rowN0 + wn * 64 + fn * 16 + (l & 15);
            const float bv = bias[col];
            float* o = out + row0 * N_DIM + col;
            o[0]                  = (float)acc[fm][fn][0] * (sr4.x * s) + bv;
            o[(size_t)1 * N_DIM]  = (float)acc[fm][fn][1] * (sr4.y * s) + bv;
            o[(size_t)2 * N_DIM]  = (float)acc[fm][fn][2] * (sr4.z * s) + bv;
            o[(size_t)3 * N_DIM]  = (float)acc[fm][fn][3] * (sr4.w * s) + bv;
        }
    }
}

// ---------- launch ----------
extern "C" void kernel_launch(void* const* d_in, const int* in_sizes, int n_in,
                              void* d_out, int out_size, void* d_ws, size_t ws_size,
                              hipStream_t stream) {
    const float* x     = (const float*)d_in[0];
    const int*   w     = (const int*)d_in[1];
    const float* scale = (const float*)d_in[2];
    const float* bias  = (const float*)d_in[3];
    float*       out   = (float*)d_out;

    const size_t x_elems = (size_t)M_DIM * K_DIM;    // 33,554,432
    const size_t w_elems = (size_t)N_DIM * K_DIM;    // 45,088,768
    const size_t xq_off  = 0;
    const size_t wq_off  = x_elems;                  // bytes (int8)
    const size_t sr_off  = x_elems + w_elems;
    if (ws_size < sr_off + (size_t)M_DIM * 4) return;

    unsigned char* xqp = (unsigned char*)d_ws + xq_off;
    unsigned char* wqp = (unsigned char*)d_ws + wq_off;
    float*         srp = (float*)((unsigned char*)d_ws + sr_off);

    quant_x_kernel<<<M_DIM, 256, 0, stream>>>(x, xqp, srp);
    {
        int n8 = (int)(w_elems / 8);
        cvt_w8_kernel<<<(n8 + 255) / 256, 256, 0, stream>>>(w, (uint2*)wqp, n8);
    }
    gemm2_kernel<<<MT2 * NT2, 512, 0, stream>>>(xqp, wqp, srp, scale, bias, out);
}

// Round 11
// 443.843 us; speedup vs baseline: 6.3942x; 6.3942x over previous
//
#include <hip/hip_runtime.h>
#include <stdint.h>

// ---------- types ----------
typedef __attribute__((ext_vector_type(4))) int   int4v;   // 4 dwords = 16 int8
typedef __attribute__((ext_vector_type(4))) float f32x4;

#define K_DIM 4096
#define N_DIM 11008
#define M_DIM 8192
#define BM 256
#define BN 256
#define BKB 128             // K-bytes (= K elems, int8) per tile
#define NT (K_DIM / BKB)    // 32 K-tiles
#define MT2 (M_DIM / BM)    // 32
#define NT2 (N_DIM / BN)    // 43

// ---------- x quantization: per-row int8, s_r = max|x_row|/127 ----------
__global__ __launch_bounds__(256) void quant_x_kernel(
    const float* __restrict__ x, unsigned char* __restrict__ xq,
    float* __restrict__ srow)
{
    const int row = blockIdx.x;                       // 0..8191
    const float4* xr = (const float4*)(x + (size_t)row * K_DIM);
    float4 v[4];
    float m = 0.f;
    #pragma unroll
    for (int i = 0; i < 4; ++i) {
        v[i] = xr[threadIdx.x + 256 * i];
        m = fmaxf(m, fmaxf(fmaxf(fabsf(v[i].x), fabsf(v[i].y)),
                           fmaxf(fabsf(v[i].z), fabsf(v[i].w))));
    }
    #pragma unroll
    for (int off = 32; off; off >>= 1) m = fmaxf(m, __shfl_xor(m, off, 64));
    __shared__ float wmax[4];
    if ((threadIdx.x & 63) == 0) wmax[threadIdx.x >> 6] = m;
    __syncthreads();
    const float mb  = fmaxf(fmaxf(wmax[0], wmax[1]), fmaxf(wmax[2], wmax[3]));
    const float s   = (mb > 0.f) ? mb * (1.f / 127.f) : 1.f;
    const float inv = (mb > 0.f) ? 127.f / mb : 0.f;
    if (threadIdx.x == 0) srow[row] = s;
    uint32_t* oq = (uint32_t*)(xq + (size_t)row * K_DIM);
    #pragma unroll
    for (int i = 0; i < 4; ++i) {
        int a = __float2int_rn(v[i].x * inv), b = __float2int_rn(v[i].y * inv);
        int c = __float2int_rn(v[i].z * inv), d = __float2int_rn(v[i].w * inv);
        oq[threadIdx.x + 256 * i] =
            (a & 0xff) | ((b & 0xff) << 8) | ((c & 0xff) << 16) | ((d & 0xff) << 24);
    }
}

// ---------- w: int32 -> int8 (exact), 8/thread ----------
__global__ void cvt_w8_kernel(const int* __restrict__ w,
                              uint2* __restrict__ wq, int n8) {
    int i = blockIdx.x * blockDim.x + threadIdx.x;
    if (i >= n8) return;
    const int4* p = (const int4*)w + 2 * (size_t)i;
    int4 a = p[0], b = p[1];
    uint32_t lo = (a.x & 0xff) | ((a.y & 0xff) << 8) | ((a.z & 0xff) << 16) | ((a.w & 0xff) << 24);
    uint32_t hi = (b.x & 0xff) | ((b.y & 0xff) << 8) | ((b.z & 0xff) << 16) | ((b.w & 0xff) << 24);
    wq[i] = (uint2){lo, hi};
}

// ---------- 256x256 int8 GEMM, 2-phase tile (3 barriers), double buffer ----------
#define GLDS16(gsrc, ldst)                                                       \
    __builtin_amdgcn_global_load_lds(                                            \
        (const __attribute__((address_space(1))) void*)(gsrc),                   \
        (__attribute__((address_space(3))) void*)(ldst), 16, 0, 0)

#define SCHED0()  __builtin_amdgcn_sched_barrier(0)
#define BARRIER() __builtin_amdgcn_s_barrier()
#define VMCNT(n)  asm volatile("s_waitcnt vmcnt(" #n ")" ::: "memory")

__global__ __launch_bounds__(512, 2) void gemm2_kernel(
    const unsigned char* __restrict__ xq,   // [8192][4096] int8
    const unsigned char* __restrict__ wq,   // [11008][4096] int8
    const float* __restrict__ srow,         // [8192] per-row x scale
    const float* __restrict__ scale,        // [1]
    const float* __restrict__ bias,         // [11008]
    float* __restrict__ out)                // [8192][11008]
{
    __shared__ unsigned char sm[131072];
    char* smc = (char*)sm;

    const int T  = threadIdx.x;
    const int l  = T & 63;
    const int wv = T >> 6;
    const int wm = wv >> 2;      // 0..1
    const int wn = wv & 3;       // 0..3

    // XCD-aware, bn-major grid map (B panel shared across XCDs via L3)
    const int orig = blockIdx.x;
    const int xcd  = orig & 7;
    const int p    = orig >> 3;          // 0..171
    const int bm   = xcd * 4 + (p & 3);  // 0..31
    const int bn   = p >> 2;             // 0..42
    const size_t rowM0 = (size_t)bm * BM;
    const size_t rowN0 = (size_t)bn * BN;

    // ---- staging precompute (pre-swizzled global source, linear LDS dest) ----
    const int rowT = T >> 3;                                          // 0..63
    const int colT = (((T & 7) * 16) ^ ((rowT & 7) << 4));            // BYTES
    const unsigned char* pAg = xq + (rowM0 + rowT) * (size_t)K_DIM + colT;
    const unsigned char* pBg = wq + (rowN0 + ((rowT >> 5) << 6) + (rowT & 31)) * (size_t)K_DIM + colT;

    auto stageA = [&](char* base, int Q, int kt) {
        #pragma unroll
        for (int c = 0; c < 2; ++c) {
            const unsigned char* src = pAg + (size_t)(c * 128 + Q * 64) * K_DIM + (size_t)kt * BKB;
            char* dst = base + Q * 16384 + c * 8192 + T * 16;
            GLDS16(src, dst);
        }
    };
    auto stageB = [&](char* base, int Q, int kt) {
        #pragma unroll
        for (int c = 0; c < 2; ++c) {
            const unsigned char* src = pBg + (size_t)(c * 128 + Q * 32) * K_DIM + (size_t)kt * BKB;
            char* dst = base + 32768 + Q * 16384 + c * 8192 + T * 16;
            GLDS16(src, dst);
        }
    };

    // ---- ds_read precompute (16x16x64 i8 fragments) ----
    const int sw     = (l & 7) << 4;
    const int inrow0 = (l >> 4) * 16;
    const int lowk0  = inrow0 ^ sw;            // k 0..63
    const int lowk1  = (64 + inrow0) ^ sw;     // k 64..127
    const int arow   = wm * 64 + (l & 15);
    const int brow   = wn * 32 + (l & 15);

    int4v acc[8][4];
    #pragma unroll
    for (int i = 0; i < 8; ++i)
        #pragma unroll
        for (int j = 0; j < 4; ++j)
            acc[i][j] = (int4v){0, 0, 0, 0};

    int4v Ah[4][2];   // current A quadrant (q0 in PA, q1 in PB)
    int4v Bh[4][2];   // Bh[0..1]=B0(cur), Bh[2..3]=B1(cur) — live across PA+PB

    char* const b0 = smc;
    char* const b1 = smc + 65536;

#define READ_A(base)                                                             \
    _Pragma("unroll")                                                            \
    for (int im = 0; im < 4; ++im) {                                             \
        Ah[im][0] = *(const int4v*)((base) + (arow + im * 16) * 128 + lowk0);    \
        Ah[im][1] = *(const int4v*)((base) + (arow + im * 16) * 128 + lowk1);    \
    }
#define READ_B(base, f0)                                                         \
    _Pragma("unroll")                                                            \
    for (int f = 0; f < 2; ++f) {                                                \
        Bh[(f0) + f][0] = *(const int4v*)((base) + (brow + f * 16) * 128 + lowk0); \
        Bh[(f0) + f][1] = *(const int4v*)((base) + (brow + f * 16) * 128 + lowk1); \
    }
// one m-half vs ALL FOUR B frags: 32 MFMA in one setprio cluster
#define MFMAH(mi)                                                                \
    __builtin_amdgcn_s_setprio(1);                                               \
    _Pragma("unroll")                                                            \
    for (int im = 0; im < 4; ++im)                                               \
        _Pragma("unroll")                                                        \
        for (int jn = 0; jn < 4; ++jn)                                           \
            _Pragma("unroll")                                                    \
            for (int kk = 0; kk < 2; ++kk)                                       \
                acc[(mi) + im][jn] = __builtin_amdgcn_mfma_i32_16x16x64_i8(      \
                    Ah[im][kk], Bh[jn][kk], acc[(mi) + im][jn], 0, 0, 0);        \
    __builtin_amdgcn_s_setprio(0);

    // 2-phase tile. Stages: A1s(t+1)=[2] at PA-head; PAs(t+2)=[6] at PB-head.
    // Steady gates both vmcnt(8) (ledger: issue order ...A1s(t),PAs(t+1),A1s(t+1),PAs(t+2)...).
    // Tails: PA-gate 0 @t=NT-1; PB-gate 2 @t=NT-2, 0 @t=NT-1.
#define TILE_BODY(bcur, bnxt, EE, STA1, STPA)                                    \
    /* PA: read Aq0,B0,B1(cur); stage A1(E+1)->bnxt; gate A1s(E); BAR; 32 MFMA */\
    READ_A(bcur);                                                                \
    READ_B((bcur) + 32768, 0);                                                   \
    READ_B((bcur) + 49152, 2);                                                   \
    if (STA1) stageA((bnxt), 1, (EE) + 1);                                       \
    if (STA1) VMCNT(8); else VMCNT(0);                                           \
    BARRIER(); SCHED0();                                                         \
    MFMAH(0);                                                                    \
    SCHED0();                                                                    \
    /* PB: read Aq1(cur); stage A0,B0,B1(E+2)->bcur; BAR; 32 MFMA; boundary */   \
    READ_A((bcur) + 16384);                                                      \
    if (STPA) { stageA((bcur), 0, (EE) + 2); stageB((bcur), 0, (EE) + 2);        \
                stageB((bcur), 1, (EE) + 2); }                                   \
    BARRIER(); SCHED0();                                                         \
    MFMAH(4);                                                                    \
    if (STPA) VMCNT(8); else { if (STA1) VMCNT(2); else VMCNT(0); }              \
    BARRIER(); SCHED0();

    // ---- prologue: PAs(0)[6], A1s(0)[2], PAs(1)[6] = 14 loads ----
    stageA(b0, 0, 0); stageB(b0, 0, 0); stageB(b0, 1, 0);
    stageA(b0, 1, 0);
    stageA(b1, 0, 1); stageB(b1, 0, 1); stageB(b1, 1, 1);
    VMCNT(8);                        // PAs(0) resident
    BARRIER(); SCHED0();

    for (int kt2 = 0; kt2 < NT / 2; ++kt2) {
        const int  E   = kt2 * 2;
        const bool stp = (E + 2 < NT);       // PAs(E+2) guard (even tile)
        // even tile E in b0: A1s(E+1) always valid (E+1 <= NT-1)
        TILE_BODY(b0, b1, E, true, stp);
        // odd tile E+1 in b1
        const bool sa1 = (E + 2 < NT);       // A1s(E+2) guard
        const bool sp1 = (E + 3 < NT);       // PAs(E+3) guard
        TILE_BODY(b1, b0, E + 1, sa1, sp1);
    }

    // ---- epilogue: y = acc * s_r * s_w + bias ----
    const float s = scale[0];
    #pragma unroll
    for (int fm = 0; fm < 8; ++fm) {
        const size_t row0 = rowM0 + wm * 128 + fm * 16 + (l >> 4) * 4;
        const float4 sr4 = *(const float4*)(srow + row0);
        #pragma unroll
        for (int fn = 0; fn < 4; ++fn) {
            const int col = (int)rowN0 + wn * 64 + fn * 16 + (l & 15);
            const float bv = bias[col];
            float* o = out + row0 * N_DIM + col;
            o[0]                  = (float)acc[fm][fn][0] * (sr4.x * s) + bv;
            o[(size_t)1 * N_DIM]  = (float)acc[fm][fn][1] * (sr4.y * s) + bv;
            o[(size_t)2 * N_DIM]  = (float)acc[fm][fn][2] * (sr4.z * s) + bv;
            o[(size_t)3 * N_DIM]  = (float)acc[fm][fn][3] * (sr4.w * s) + bv;
        }
    }
}

// ---------- launch ----------
extern "C" void kernel_launch(void* const* d_in, const int* in_sizes, int n_in,
                              void* d_out, int out_size, void* d_ws, size_t ws_size,
                              hipStream_t stream) {
    const float* x     = (const float*)d_in[0];
    const int*   w     = (const int*)d_in[1];
    const float* scale = (const float*)d_in[2];
    const float* bias  = (const float*)d_in[3];
    float*       out   = (float*)d_out;

    const size_t x_elems = (size_t)M_DIM * K_DIM;    // 33,554,432
    const size_t w_elems = (size_t)N_DIM * K_DIM;    // 45,088,768
    const size_t xq_off  = 0;
    const size_t wq_off  = x_elems;                  // bytes (int8)
    const size_t sr_off  = x_elems + w_elems;
    if (ws_size < sr_off + (size_t)M_DIM * 4) return;

    unsigned char* xqp = (unsigned char*)d_ws + xq_off;
    unsigned char* wqp = (unsigned char*)d_ws + wq_off;
    float*         srp = (float*)((unsigned char*)d_ws + sr_off);

    quant_x_kernel<<<M_DIM, 256, 0, stream>>>(x, xqp, srp);
    {
        int n8 = (int)(w_elems / 8);
        cvt_w8_kernel<<<(n8 + 255) / 256, 256, 0, stream>>>(w, (uint2*)wqp, n8);
    }
    gemm2_kernel<<<MT2 * NT2, 512, 0, stream>>>(xqp, wqp, srp, scale, bias, out);
}

// Round 12
// 431.670 us; speedup vs baseline: 6.5745x; 1.0282x over previous
//
#include <hip/hip_runtime.h>
#include <stdint.h>

// ---------- types ----------
typedef __attribute__((ext_vector_type(4))) int   int4v;   // 4 dwords = 16 int8
typedef __attribute__((ext_vector_type(4))) float f32x4;

#define K_DIM 4096
#define N_DIM 11008
#define M_DIM 8192
#define BM 256
#define BN 256
#define BKB 128             // K-bytes (= K elems, int8) per tile
#define NT (K_DIM / BKB)    // 32 K-tiles
#define MT2 (M_DIM / BM)    // 32
#define NT2 (N_DIM / BN)    // 43
#define N8W ((N_DIM * K_DIM) / 8)        // 5,636,096 (= 22016 * 256)
#define CVT_BLOCKS (N8W / 256)           // 22016

// ---------- fused prep: x row-quant (blocks 0..8191) + w int32->int8 ----------
__global__ __launch_bounds__(256) void prep_kernel(
    const float* __restrict__ x, unsigned char* __restrict__ xq,
    float* __restrict__ srow,
    const int* __restrict__ w, uint2* __restrict__ wq)
{
    __shared__ float wmax[4];
    const int b = blockIdx.x;
    if (b < M_DIM) {
        // ---- per-row int8 quant, s_r = max|x_row|/127 ----
        const int row = b;
        const float4* xr = (const float4*)(x + (size_t)row * K_DIM);
        float4 v[4];
        float m = 0.f;
        #pragma unroll
        for (int i = 0; i < 4; ++i) {
            v[i] = xr[threadIdx.x + 256 * i];
            m = fmaxf(m, fmaxf(fmaxf(fabsf(v[i].x), fabsf(v[i].y)),
                               fmaxf(fabsf(v[i].z), fabsf(v[i].w))));
        }
        #pragma unroll
        for (int off = 32; off; off >>= 1) m = fmaxf(m, __shfl_xor(m, off, 64));
        if ((threadIdx.x & 63) == 0) wmax[threadIdx.x >> 6] = m;
        __syncthreads();
        const float mb  = fmaxf(fmaxf(wmax[0], wmax[1]), fmaxf(wmax[2], wmax[3]));
        const float s   = (mb > 0.f) ? mb * (1.f / 127.f) : 1.f;
        const float inv = (mb > 0.f) ? 127.f / mb : 0.f;
        if (threadIdx.x == 0) srow[row] = s;
        uint32_t* oq = (uint32_t*)(xq + (size_t)row * K_DIM);
        #pragma unroll
        for (int i = 0; i < 4; ++i) {
            int a = __float2int_rn(v[i].x * inv), bb = __float2int_rn(v[i].y * inv);
            int c = __float2int_rn(v[i].z * inv), d  = __float2int_rn(v[i].w * inv);
            oq[threadIdx.x + 256 * i] =
                (a & 0xff) | ((bb & 0xff) << 8) | ((c & 0xff) << 16) | ((d & 0xff) << 24);
        }
    } else {
        // ---- w: int32 -> int8 (exact), 8 elems/thread ----
        const int i = (b - M_DIM) * 256 + threadIdx.x;
        if (i < N8W) {
            const int4* p = (const int4*)w + 2 * (size_t)i;
            int4 a = p[0], bb = p[1];
            uint32_t lo = (a.x & 0xff) | ((a.y & 0xff) << 8) |
                          ((a.z & 0xff) << 16) | ((a.w & 0xff) << 24);
            uint32_t hi = (bb.x & 0xff) | ((bb.y & 0xff) << 8) |
                          ((bb.z & 0xff) << 16) | ((bb.w & 0xff) << 24);
            wq[i] = (uint2){lo, hi};
        }
    }
}

// ---------- 256x256 int8 GEMM, R8 schedule (proven best) ----------
#define GLDS16(gsrc, ldst)                                                       \
    __builtin_amdgcn_global_load_lds(                                            \
        (const __attribute__((address_space(1))) void*)(gsrc),                   \
        (__attribute__((address_space(3))) void*)(ldst), 16, 0, 0)

#define SCHED0()  __builtin_amdgcn_sched_barrier(0)
#define BARSCHED() do { __builtin_amdgcn_s_barrier(); SCHED0(); } while (0)
#define VMCNT(n)  asm volatile("s_waitcnt vmcnt(" #n ")" ::: "memory")

__global__ __launch_bounds__(512, 2) void gemm2_kernel(
    const unsigned char* __restrict__ xq,   // [8192][4096] int8
    const unsigned char* __restrict__ wq,   // [11008][4096] int8
    const float* __restrict__ srow,         // [8192] per-row x scale
    const float* __restrict__ scale,        // [1]
    const float* __restrict__ bias,         // [11008]
    float* __restrict__ out)                // [8192][11008]
{
    __shared__ unsigned char sm[131072];
    char* smc = (char*)sm;

    const int T  = threadIdx.x;
    const int l  = T & 63;
    const int wv = T >> 6;
    const int wm = wv >> 2;      // 0..1
    const int wn = wv & 3;       // 0..3

    // XCD-aware, bn-major grid map (B panel shared across XCDs via L3)
    const int orig = blockIdx.x;
    const int xcd  = orig & 7;
    const int p    = orig >> 3;          // 0..171
    const int bm   = xcd * 4 + (p & 3);  // 0..31
    const int bn   = p >> 2;             // 0..42
    const size_t rowM0 = (size_t)bm * BM;
    const size_t rowN0 = (size_t)bn * BN;

    // ---- staging precompute (pre-swizzled global source, linear LDS dest) ----
    const int rowT = T >> 3;                                          // 0..63
    const int colT = (((T & 7) * 16) ^ ((rowT & 7) << 4));            // BYTES
    const unsigned char* pAg = xq + (rowM0 + rowT) * (size_t)K_DIM + colT;
    const unsigned char* pBg = wq + (rowN0 + ((rowT >> 5) << 6) + (rowT & 31)) * (size_t)K_DIM + colT;

    auto stageA = [&](char* base, int Q, int kt) {
        #pragma unroll
        for (int c = 0; c < 2; ++c) {
            const unsigned char* src = pAg + (size_t)(c * 128 + Q * 64) * K_DIM + (size_t)kt * BKB;
            char* dst = base + Q * 16384 + c * 8192 + T * 16;
            GLDS16(src, dst);
        }
    };
    auto stageB = [&](char* base, int Q, int kt) {
        #pragma unroll
        for (int c = 0; c < 2; ++c) {
            const unsigned char* src = pBg + (size_t)(c * 128 + Q * 32) * K_DIM + (size_t)kt * BKB;
            char* dst = base + 32768 + Q * 16384 + c * 8192 + T * 16;
            GLDS16(src, dst);
        }
    };

    // ---- ds_read precompute (16x16x64 i8 fragments) ----
    const int sw     = (l & 7) << 4;
    const int inrow0 = (l >> 4) * 16;
    const int lowk0  = inrow0 ^ sw;            // k 0..63
    const int lowk1  = (64 + inrow0) ^ sw;     // k 64..127
    const int arow   = wm * 64 + (l & 15);
    const int brow   = wn * 32 + (l & 15);

    int4v acc[8][4];
    #pragma unroll
    for (int i = 0; i < 8; ++i)
        #pragma unroll
        for (int j = 0; j < 4; ++j)
            acc[i][j] = (int4v){0, 0, 0, 0};

    int4v Ah[4][2];   // current A quadrant
    int4v Bh[4][2];   // Bh[0..1]=B0(cur), Bh[2..3]=B1(cur)

    char* const b0 = smc;
    char* const b1 = smc + 65536;

#define READ_A(base)                                                             \
    _Pragma("unroll")                                                            \
    for (int im = 0; im < 4; ++im) {                                             \
        Ah[im][0] = *(const int4v*)((base) + (arow + im * 16) * 128 + lowk0);    \
        Ah[im][1] = *(const int4v*)((base) + (arow + im * 16) * 128 + lowk1);    \
    }
#define READ_B(base, f0)                                                         \
    _Pragma("unroll")                                                            \
    for (int f = 0; f < 2; ++f) {                                                \
        Bh[(f0) + f][0] = *(const int4v*)((base) + (brow + f * 16) * 128 + lowk0); \
        Bh[(f0) + f][1] = *(const int4v*)((base) + (brow + f * 16) * 128 + lowk1); \
    }
#define MFMAQ(mi, ni)                                                            \
    __builtin_amdgcn_s_setprio(1);                                               \
    _Pragma("unroll")                                                            \
    for (int im = 0; im < 4; ++im)                                               \
        _Pragma("unroll")                                                        \
        for (int jn = 0; jn < 2; ++jn)                                           \
            _Pragma("unroll")                                                    \
            for (int kk = 0; kk < 2; ++kk)                                       \
                acc[(mi) + im][(ni) + jn] = __builtin_amdgcn_mfma_i32_16x16x64_i8( \
                    Ah[im][kk], Bh[(ni) + jn][kk], acc[(mi) + im][(ni) + jn], 0, 0, 0); \
    __builtin_amdgcn_s_setprio(0);

    // R8 tile schedule (5 barriers/tile, gate->barrier->read discipline)
#define TILE_BODY(bcur, bnxt, EE, ST0, STN, RD)                                  \
    READ_B((bcur) + 32768 + 16384, 2);                                           \
    if (ST0) stageA((bnxt), 1, (EE) + 1);                                        \
    BARSCHED();                                                                  \
    MFMAQ(0, 0);                                                                 \
    SCHED0();                                                                    \
    if (STN) stageA((bcur), 0, (EE) + 2);                                        \
    BARSCHED();                                                                  \
    MFMAQ(0, 2);                                                                 \
    READ_A((bcur) + 16384);                                                      \
    SCHED0();                                                                    \
    if (STN) stageB((bcur), 0, (EE) + 2);                                        \
    BARSCHED();                                                                  \
    MFMAQ(4, 0);                                                                 \
    if (STN) VMCNT(8); else VMCNT(4);                                            \
    SCHED0();                                                                    \
    if (STN) stageB((bcur), 1, (EE) + 2);                                        \
    BARSCHED();                                                                  \
    MFMAQ(4, 2);                                                                 \
    if (RD) { READ_A(bnxt); READ_B((bnxt) + 32768, 0); }                         \
    if (STN) VMCNT(6); else VMCNT(0);                                            \
    __builtin_amdgcn_s_barrier();                                                \
    SCHED0();

    // ---- prologue: [A0(0),B0(0),B1(0),A1(0),A0(1),B0(1),B1(1)] = 14 loads ----
    stageA(b0, 0, 0); stageB(b0, 0, 0); stageB(b0, 1, 0); stageA(b0, 1, 0);
    stageA(b1, 0, 1); stageB(b1, 0, 1); stageB(b1, 1, 1);
    VMCNT(8);                        // A0/B0/B1(0) resident
    __builtin_amdgcn_s_barrier();
    SCHED0();
    READ_A(b0);                      // Aq0(0)
    READ_B(b0 + 32768, 0);           // B0(0)
    VMCNT(6);                        // A1(0) resident
    SCHED0();

    for (int kt2 = 0; kt2 < NT / 2; ++kt2) {
        const int  E  = kt2 * 2;
        const bool st = (kt2 < NT / 2 - 1);
        TILE_BODY(b0, b1, E, true, st, true);
        TILE_BODY(b1, b0, E + 1, st, st, st);
    }

    // ---- epilogue: y = acc * s_r * s_w + bias ----
    const float s = scale[0];
    #pragma unroll
    for (int fm = 0; fm < 8; ++fm) {
        const size_t row0 = rowM0 + wm * 128 + fm * 16 + (l >> 4) * 4;
        const float4 sr4 = *(const float4*)(srow + row0);
        #pragma unroll
        for (int fn = 0; fn < 4; ++fn) {
            const int col = (int)rowN0 + wn * 64 + fn * 16 + (l & 15);
            const float bv = bias[col];
            float* o = out + row0 * N_DIM + col;
            o[0]                  = (float)acc[fm][fn][0] * (sr4.x * s) + bv;
            o[(size_t)1 * N_DIM]  = (float)acc[fm][fn][1] * (sr4.y * s) + bv;
            o[(size_t)2 * N_DIM]  = (float)acc[fm][fn][2] * (sr4.z * s) + bv;
            o[(size_t)3 * N_DIM]  = (float)acc[fm][fn][3] * (sr4.w * s) + bv;
        }
    }
}

// ---------- launch ----------
extern "C" void kernel_launch(void* const* d_in, const int* in_sizes, int n_in,
                              void* d_out, int out_size, void* d_ws, size_t ws_size,
                              hipStream_t stream) {
    const float* x     = (const float*)d_in[0];
    const int*   w     = (const int*)d_in[1];
    const float* scale = (const float*)d_in[2];
    const float* bias  = (const float*)d_in[3];
    float*       out   = (float*)d_out;

    const size_t x_elems = (size_t)M_DIM * K_DIM;    // 33,554,432
    const size_t w_elems = (size_t)N_DIM * K_DIM;    // 45,088,768
    const size_t xq_off  = 0;
    const size_t wq_off  = x_elems;                  // bytes (int8)
    const size_t sr_off  = x_elems + w_elems;
    if (ws_size < sr_off + (size_t)M_DIM * 4) return;

    unsigned char* xqp = (unsigned char*)d_ws + xq_off;
    unsigned char* wqp = (unsigned char*)d_ws + wq_off;
    float*         srp = (float*)((unsigned char*)d_ws + sr_off);

    prep_kernel<<<M_DIM + CVT_BLOCKS, 256, 0, stream>>>(
        x, xqp, srp, w, (uint2*)wqp);
    gemm2_kernel<<<MT2 * NT2, 512, 0, stream>>>(xqp, wqp, srp, scale, bias, out);
}

// Round 13
// 430.063 us; speedup vs baseline: 6.5991x; 1.0037x over previous
//
#include <hip/hip_runtime.h>
#include <stdint.h>

// ---------- types ----------
typedef __attribute__((ext_vector_type(4))) int   int4v;   // 4 dwords = 16 int8
typedef __attribute__((ext_vector_type(4))) float f32x4;

#define K_DIM 4096
#define N_DIM 11008
#define M_DIM 8192
#define BM 256
#define BN 256
#define BKB 128             // K-bytes (= K elems, int8) per tile
#define NT (K_DIM / BKB)    // 32 K-tiles
#define MT2 (M_DIM / BM)    // 32
#define NT2 (N_DIM / BN)    // 43
#define N16W ((N_DIM * K_DIM) / 16)      // 2,818,048 (= 11008 * 256)
#define CVT_BLOCKS (N16W / 256)          // 11008

// ---------- fused prep: x row-quant (blocks 0..8191) + w int32->int8 ----------
__global__ __launch_bounds__(256) void prep_kernel(
    const float* __restrict__ x, unsigned char* __restrict__ xq,
    float* __restrict__ srow,
    const int* __restrict__ w, uint4* __restrict__ wq)
{
    __shared__ float wmax[4];
    const int b = blockIdx.x;
    if (b < M_DIM) {
        // ---- per-row int8 quant, s_r = max|x_row|/127 ----
        // thread t owns contiguous elems [t*16, t*16+16)
        const int row = b;
        const float4* xr = (const float4*)(x + (size_t)row * K_DIM) + threadIdx.x * 4;
        float4 v[4];
        float m = 0.f;
        #pragma unroll
        for (int i = 0; i < 4; ++i) {
            v[i] = xr[i];
            m = fmaxf(m, fmaxf(fmaxf(fabsf(v[i].x), fabsf(v[i].y)),
                               fmaxf(fabsf(v[i].z), fabsf(v[i].w))));
        }
        #pragma unroll
        for (int off = 32; off; off >>= 1) m = fmaxf(m, __shfl_xor(m, off, 64));
        if ((threadIdx.x & 63) == 0) wmax[threadIdx.x >> 6] = m;
        __syncthreads();
        const float mb  = fmaxf(fmaxf(wmax[0], wmax[1]), fmaxf(wmax[2], wmax[3]));
        const float s   = (mb > 0.f) ? mb * (1.f / 127.f) : 1.f;
        const float inv = (mb > 0.f) ? 127.f / mb : 0.f;
        if (threadIdx.x == 0) srow[row] = s;
        uint32_t q[4];
        #pragma unroll
        for (int i = 0; i < 4; ++i) {
            int a = __float2int_rn(v[i].x * inv), bb = __float2int_rn(v[i].y * inv);
            int c = __float2int_rn(v[i].z * inv), d  = __float2int_rn(v[i].w * inv);
            q[i] = (a & 0xff) | ((bb & 0xff) << 8) | ((c & 0xff) << 16) | ((d & 0xff) << 24);
        }
        ((uint4*)(xq + (size_t)row * K_DIM))[threadIdx.x] =
            (uint4){q[0], q[1], q[2], q[3]};
    } else {
        // ---- w: int32 -> int8 (exact), 16 elems/thread, one 16B store ----
        const size_t i = (size_t)(b - M_DIM) * 256 + threadIdx.x;   // < N16W
        const int4* p = (const int4*)w + 4 * i;
        uint32_t q[4];
        #pragma unroll
        for (int j = 0; j < 4; ++j) {
            int4 a = p[j];
            q[j] = (a.x & 0xff) | ((a.y & 0xff) << 8) |
                   ((a.z & 0xff) << 16) | ((a.w & 0xff) << 24);
        }
        wq[i] = (uint4){q[0], q[1], q[2], q[3]};
    }
}

// ---------- 256x256 int8 GEMM, R8 schedule (proven best) ----------
#define GLDS16(gsrc, ldst)                                                       \
    __builtin_amdgcn_global_load_lds(                                            \
        (const __attribute__((address_space(1))) void*)(gsrc),                   \
        (__attribute__((address_space(3))) void*)(ldst), 16, 0, 0)

#define SCHED0()  __builtin_amdgcn_sched_barrier(0)
#define BARSCHED() do { __builtin_amdgcn_s_barrier(); SCHED0(); } while (0)
#define VMCNT(n)  asm volatile("s_waitcnt vmcnt(" #n ")" ::: "memory")

__global__ __launch_bounds__(512, 2) void gemm2_kernel(
    const unsigned char* __restrict__ xq,   // [8192][4096] int8
    const unsigned char* __restrict__ wq,   // [11008][4096] int8
    const float* __restrict__ srow,         // [8192] per-row x scale
    const float* __restrict__ scale,        // [1]
    const float* __restrict__ bias,         // [11008]
    float* __restrict__ out)                // [8192][11008]
{
    __shared__ unsigned char sm[131072];
    char* smc = (char*)sm;

    const int T  = threadIdx.x;
    const int l  = T & 63;
    const int wv = T >> 6;
    const int wm = wv >> 2;      // 0..1
    const int wn = wv & 3;       // 0..3

    // XCD-aware, bn-major grid map (B panel shared across XCDs via L3)
    const int orig = blockIdx.x;
    const int xcd  = orig & 7;
    const int p    = orig >> 3;          // 0..171
    const int bm   = xcd * 4 + (p & 3);  // 0..31
    const int bn   = p >> 2;             // 0..42
    const size_t rowM0 = (size_t)bm * BM;
    const size_t rowN0 = (size_t)bn * BN;

    // ---- staging precompute (pre-swizzled global source, linear LDS dest) ----
    const int rowT = T >> 3;                                          // 0..63
    const int colT = (((T & 7) * 16) ^ ((rowT & 7) << 4));            // BYTES
    const unsigned char* pAg = xq + (rowM0 + rowT) * (size_t)K_DIM + colT;
    const unsigned char* pBg = wq + (rowN0 + ((rowT >> 5) << 6) + (rowT & 31)) * (size_t)K_DIM + colT;

    auto stageA = [&](char* base, int Q, int kt) {
        #pragma unroll
        for (int c = 0; c < 2; ++c) {
            const unsigned char* src = pAg + (size_t)(c * 128 + Q * 64) * K_DIM + (size_t)kt * BKB;
            char* dst = base + Q * 16384 + c * 8192 + T * 16;
            GLDS16(src, dst);
        }
    };
    auto stageB = [&](char* base, int Q, int kt) {
        #pragma unroll
        for (int c = 0; c < 2; ++c) {
            const unsigned char* src = pBg + (size_t)(c * 128 + Q * 32) * K_DIM + (size_t)kt * BKB;
            char* dst = base + 32768 + Q * 16384 + c * 8192 + T * 16;
            GLDS16(src, dst);
        }
    };

    // ---- ds_read precompute (16x16x64 i8 fragments) ----
    const int sw     = (l & 7) << 4;
    const int inrow0 = (l >> 4) * 16;
    const int lowk0  = inrow0 ^ sw;            // k 0..63
    const int lowk1  = (64 + inrow0) ^ sw;     // k 64..127
    const int arow   = wm * 64 + (l & 15);
    const int brow   = wn * 32 + (l & 15);

    int4v acc[8][4];
    #pragma unroll
    for (int i = 0; i < 8; ++i)
        #pragma unroll
        for (int j = 0; j < 4; ++j)
            acc[i][j] = (int4v){0, 0, 0, 0};

    int4v Ah[4][2];   // current A quadrant
    int4v Bh[4][2];   // Bh[0..1]=B0(cur), Bh[2..3]=B1(cur)

    char* const b0 = smc;
    char* const b1 = smc + 65536;

#define READ_A(base)                                                             \
    _Pragma("unroll")                                                            \
    for (int im = 0; im < 4; ++im) {                                             \
        Ah[im][0] = *(const int4v*)((base) + (arow + im * 16) * 128 + lowk0);    \
        Ah[im][1] = *(const int4v*)((base) + (arow + im * 16) * 128 + lowk1);    \
    }
#define READ_B(base, f0)                                                         \
    _Pragma("unroll")                                                            \
    for (int f = 0; f < 2; ++f) {                                                \
        Bh[(f0) + f][0] = *(const int4v*)((base) + (brow + f * 16) * 128 + lowk0); \
        Bh[(f0) + f][1] = *(const int4v*)((base) + (brow + f * 16) * 128 + lowk1); \
    }
#define MFMAQ(mi, ni)                                                            \
    __builtin_amdgcn_s_setprio(1);                                               \
    _Pragma("unroll")                                                            \
    for (int im = 0; im < 4; ++im)                                               \
        _Pragma("unroll")                                                        \
        for (int jn = 0; jn < 2; ++jn)                                           \
            _Pragma("unroll")                                                    \
            for (int kk = 0; kk < 2; ++kk)                                       \
                acc[(mi) + im][(ni) + jn] = __builtin_amdgcn_mfma_i32_16x16x64_i8( \
                    Ah[im][kk], Bh[(ni) + jn][kk], acc[(mi) + im][(ni) + jn], 0, 0, 0); \
    __builtin_amdgcn_s_setprio(0);

    // R8 tile schedule (5 barriers/tile, gate->barrier->read discipline)
#define TILE_BODY(bcur, bnxt, EE, ST0, STN, RD)                                  \
    READ_B((bcur) + 32768 + 16384, 2);                                           \
    if (ST0) stageA((bnxt), 1, (EE) + 1);                                        \
    BARSCHED();                                                                  \
    MFMAQ(0, 0);                                                                 \
    SCHED0();                                                                    \
    if (STN) stageA((bcur), 0, (EE) + 2);                                        \
    BARSCHED();                                                                  \
    MFMAQ(0, 2);                                                                 \
    READ_A((bcur) + 16384);                                                      \
    SCHED0();                                                                    \
    if (STN) stageB((bcur), 0, (EE) + 2);                                        \
    BARSCHED();                                                                  \
    MFMAQ(4, 0);                                                                 \
    if (STN) VMCNT(8); else VMCNT(4);                                            \
    SCHED0();                                                                    \
    if (STN) stageB((bcur), 1, (EE) + 2);                                        \
    BARSCHED();                                                                  \
    MFMAQ(4, 2);                                                                 \
    if (RD) { READ_A(bnxt); READ_B((bnxt) + 32768, 0); }                         \
    if (STN) VMCNT(6); else VMCNT(0);                                            \
    __builtin_amdgcn_s_barrier();                                                \
    SCHED0();

    // ---- prologue: [A0(0),B0(0),B1(0),A1(0),A0(1),B0(1),B1(1)] = 14 loads ----
    stageA(b0, 0, 0); stageB(b0, 0, 0); stageB(b0, 1, 0); stageA(b0, 1, 0);
    stageA(b1, 0, 1); stageB(b1, 0, 1); stageB(b1, 1, 1);
    VMCNT(8);                        // A0/B0/B1(0) resident
    __builtin_amdgcn_s_barrier();
    SCHED0();
    READ_A(b0);                      // Aq0(0)
    READ_B(b0 + 32768, 0);           // B0(0)
    VMCNT(6);                        // A1(0) resident
    SCHED0();

    for (int kt2 = 0; kt2 < NT / 2; ++kt2) {
        const int  E  = kt2 * 2;
        const bool st = (kt2 < NT / 2 - 1);
        TILE_BODY(b0, b1, E, true, st, true);
        TILE_BODY(b1, b0, E + 1, st, st, st);
    }

    // ---- epilogue: y = acc * s_r * s_w + bias ----
    const float s = scale[0];
    #pragma unroll
    for (int fm = 0; fm < 8; ++fm) {
        const size_t row0 = rowM0 + wm * 128 + fm * 16 + (l >> 4) * 4;
        const float4 sr4 = *(const float4*)(srow + row0);
        #pragma unroll
        for (int fn = 0; fn < 4; ++fn) {
            const int col = (int)rowN0 + wn * 64 + fn * 16 + (l & 15);
            const float bv = bias[col];
            float* o = out + row0 * N_DIM + col;
            o[0]                  = (float)acc[fm][fn][0] * (sr4.x * s) + bv;
            o[(size_t)1 * N_DIM]  = (float)acc[fm][fn][1] * (sr4.y * s) + bv;
            o[(size_t)2 * N_DIM]  = (float)acc[fm][fn][2] * (sr4.z * s) + bv;
            o[(size_t)3 * N_DIM]  = (float)acc[fm][fn][3] * (sr4.w * s) + bv;
        }
    }
}

// ---------- launch ----------
extern "C" void kernel_launch(void* const* d_in, const int* in_sizes, int n_in,
                              void* d_out, int out_size, void* d_ws, size_t ws_size,
                              hipStream_t stream) {
    const float* x     = (const float*)d_in[0];
    const int*   w     = (const int*)d_in[1];
    const float* scale = (const float*)d_in[2];
    const float* bias  = (const float*)d_in[3];
    float*       out   = (float*)d_out;

    const size_t x_elems = (size_t)M_DIM * K_DIM;    // 33,554,432
    const size_t w_elems = (size_t)N_DIM * K_DIM;    // 45,088,768
    const size_t xq_off  = 0;
    const size_t wq_off  = x_elems;                  // bytes (int8)
    const size_t sr_off  = x_elems + w_elems;
    if (ws_size < sr_off + (size_t)M_DIM * 4) return;

    unsigned char* xqp = (unsigned char*)d_ws + xq_off;
    unsigned char* wqp = (unsigned char*)d_ws + wq_off;
    float*         srp = (float*)((unsigned char*)d_ws + sr_off);

    prep_kernel<<<M_DIM + CVT_BLOCKS, 256, 0, stream>>>(
        x, xqp, srp, w, (uint4*)wqp);
    gemm2_kernel<<<MT2 * NT2, 512, 0, stream>>>(xqp, wqp, srp, scale, bias, out);
}